// Round 11
// baseline (1101.369 us; speedup 1.0000x reference)
//
#include <hip/hip_runtime.h>
#include <hip/hip_bf16.h>
#include <math.h>

#define TOKENS 2048
#define HIDDEN 2048
#define NH 16
#define HD 128
#define SEQ 1024
#define MOE_I 1408
#define SH_I 5632
#define K3 6144
#define MAXROWS 5120

typedef __hip_bfloat16 bf16;
typedef short bf16x8 __attribute__((ext_vector_type(8)));
typedef short bf16x4 __attribute__((ext_vector_type(4)));
typedef float f32x4 __attribute__((ext_vector_type(4)));
typedef float f32x16 __attribute__((ext_vector_type(16)));

__device__ __forceinline__ float b2f(bf16 x) { return __bfloat162float(x); }
__device__ __forceinline__ bf16 f2b(float x) { return __float2bfloat16(x); }
__device__ __forceinline__ void split2(float v, short& hi, short& lo) {
    bf16 h = f2b(v);
    bf16 l = f2b(v - b2f(h));
    hi = __builtin_bit_cast(short, h); lo = __builtin_bit_cast(short, l);
}

__device__ __forceinline__ void load_lds16(const void* g, void* l) {
    __builtin_amdgcn_global_load_lds(
        (const __attribute__((address_space(1))) unsigned int*)g,
        (__attribute__((address_space(3))) unsigned int*)l, 16, 0, 0);
}

// ---------------------------------------------------------------------------
__global__ __launch_bounds__(256) void rmsnorm3_k(
    const float* __restrict__ x, const float* __restrict__ w, bf16* __restrict__ out)
{
    const int row = blockIdx.x, tid = threadIdx.x;
    const float4* xr = (const float4*)(x + (size_t)row * HIDDEN);
    float4 v1 = xr[tid], v2 = xr[tid + 256];
    float ss = v1.x*v1.x + v1.y*v1.y + v1.z*v1.z + v1.w*v1.w
             + v2.x*v2.x + v2.y*v2.y + v2.z*v2.z + v2.w*v2.w;
    #pragma unroll
    for (int off = 1; off < 64; off <<= 1) ss += __shfl_xor(ss, off);
    __shared__ float ps[4];
    if ((tid & 63) == 0) ps[tid >> 6] = ss;
    __syncthreads();
    float tot = ps[0] + ps[1] + ps[2] + ps[3];
    float r = rsqrtf(tot * (1.0f / HIDDEN) + 1e-6f);
    bf16* o = out + (size_t)row * 4096;
    float vv[8] = {v1.x, v1.y, v1.z, v1.w, v2.x, v2.y, v2.z, v2.w};
    int idx[8]  = {tid*4, tid*4+1, tid*4+2, tid*4+3,
                   1024+tid*4, 1024+tid*4+1, 1024+tid*4+2, 1024+tid*4+3};
    #pragma unroll
    for (int u = 0; u < 8; u++) {
        short hi, lo; split2(vv[u] * r * w[idx[u]], hi, lo);
        o[idx[u]]        = __builtin_bit_cast(bf16, hi);
        o[2048 + idx[u]] = __builtin_bit_cast(bf16, lo);
    }
}

// ---------------------------------------------------------------------------
__global__ __launch_bounds__(256) void transpose64_k(
    const float* __restrict__ W, bf16* __restrict__ Wt, int K, int N,
    long zsrc, long zdst)
{
    __shared__ float t[64][65];
    W  += (size_t)blockIdx.z * zsrc;
    Wt += (size_t)blockIdx.z * zdst;
    const int n0 = blockIdx.x * 64, k0 = blockIdx.y * 64;
    const int tid = threadIdx.x;
    #pragma unroll
    for (int i = 0; i < 4; i++) {
        const int idx = tid + 256*i;
        const int r = idx >> 4, q = idx & 15;
        float4 v = *(const float4*)(W + (size_t)(k0 + r) * N + n0 + q*4);
        t[r][q*4+0] = v.x; t[r][q*4+1] = v.y; t[r][q*4+2] = v.z; t[r][q*4+3] = v.w;
    }
    __syncthreads();
    #pragma unroll
    for (int i = 0; i < 4; i++) {
        const int idx = tid + 256*i;
        const int nl = idx >> 4, kc = idx & 15;
        bf16x4 o4;
        #pragma unroll
        for (int j = 0; j < 4; j++)
            o4[j] = __builtin_bit_cast(short, f2b(t[kc*4+j][nl]));
        *(bf16x4*)(Wt + (size_t)(n0 + nl) * K + k0 + kc*4) = o4;
    }
}

__global__ __launch_bounds__(256) void transpose_qkvo_k(
    const float* __restrict__ wq, const float* __restrict__ wk,
    const float* __restrict__ wv, const float* __restrict__ wo,
    bf16* __restrict__ wtqkv, bf16* __restrict__ wt3o)
{
    const int z = blockIdx.z;
    const float* W = (z == 0) ? wq : (z == 1) ? wk : (z == 2) ? wv : wo;
    bf16* Wt2 = (z < 3) ? wtqkv : wt3o;
    const int nOff = (z < 3) ? z * 2048 : 0;
    __shared__ float t[64][65];
    const int n0 = blockIdx.x * 64, k0 = blockIdx.y * 64;
    const int tid = threadIdx.x;
    #pragma unroll
    for (int i = 0; i < 4; i++) {
        const int idx = tid + 256*i;
        const int r = idx >> 4, q = idx & 15;
        float4 v = *(const float4*)(W + (size_t)(k0 + r) * 2048 + n0 + q*4);
        t[r][q*4+0] = v.x; t[r][q*4+1] = v.y; t[r][q*4+2] = v.z; t[r][q*4+3] = v.w;
    }
    __syncthreads();
    #pragma unroll
    for (int i = 0; i < 4; i++) {
        const int idx = tid + 256*i;
        const int nl = idx >> 4, kc = idx & 15;
        bf16x4 h4, l4;
        #pragma unroll
        for (int j = 0; j < 4; j++) {
            short hi, lo; split2(t[kc*4+j][nl], hi, lo);
            h4[j] = hi; l4[j] = lo;
        }
        bf16* o = Wt2 + (size_t)(nOff + n0 + nl) * 4096 + k0 + kc*4;
        *(bf16x4*)o = h4;
        *(bf16x4*)(o + 2048) = l4;
    }
}

__global__ __launch_bounds__(256) void transpose_moegu_k(
    const float* __restrict__ ge, const float* __restrict__ ue, bf16* __restrict__ wtgu)
{
    const int z = blockIdx.z, e = z & 7, isUp = z >> 3;
    const float* W = (isUp ? ue : ge) + (size_t)e * HIDDEN * MOE_I;
    bf16* Wt = wtgu + (size_t)e * 2816 * HIDDEN;
    __shared__ float t[64][65];
    const int n0 = blockIdx.x * 64, k0 = blockIdx.y * 64;
    const int tid = threadIdx.x;
    #pragma unroll
    for (int i = 0; i < 4; i++) {
        const int idx = tid + 256*i;
        const int r = idx >> 4, q = idx & 15;
        float4 v = *(const float4*)(W + (size_t)(k0 + r) * MOE_I + n0 + q*4);
        t[r][q*4+0] = v.x; t[r][q*4+1] = v.y; t[r][q*4+2] = v.z; t[r][q*4+3] = v.w;
    }
    __syncthreads();
    #pragma unroll
    for (int i = 0; i < 4; i++) {
        const int idx = tid + 256*i;
        const int nl = idx >> 4, kc = idx & 15;
        bf16x4 o4;
        #pragma unroll
        for (int j = 0; j < 4; j++)
            o4[j] = __builtin_bit_cast(short, f2b(t[kc*4+j][nl]));
        *(bf16x4*)(Wt + (size_t)(2*(n0 + nl) + isUp) * 2048 + k0 + kc*4) = o4;
    }
}

__global__ __launch_bounds__(256) void transpose_shgu_k(
    const float* __restrict__ sg, const float* __restrict__ su, bf16* __restrict__ dst)
{
    const int isUp = blockIdx.z;
    const float* W = isUp ? su : sg;
    __shared__ float t[64][65];
    const int n0 = blockIdx.x * 64, k0 = blockIdx.y * 64;
    const int tid = threadIdx.x;
    #pragma unroll
    for (int i = 0; i < 4; i++) {
        const int idx = tid + 256*i;
        const int r = idx >> 4, q = idx & 15;
        float4 v = *(const float4*)(W + (size_t)(k0 + r) * SH_I + n0 + q*4);
        t[r][q*4+0] = v.x; t[r][q*4+1] = v.y; t[r][q*4+2] = v.z; t[r][q*4+3] = v.w;
    }
    __syncthreads();
    #pragma unroll
    for (int i = 0; i < 4; i++) {
        const int idx = tid + 256*i;
        const int nl = idx >> 4, kc = idx & 15;
        bf16x4 o4;
        #pragma unroll
        for (int j = 0; j < 4; j++)
            o4[j] = __builtin_bit_cast(short, f2b(t[kc*4+j][nl]));
        *(bf16x4*)(dst + (size_t)(2*(n0 + nl) + isUp) * 2048 + k0 + kc*4) = o4;
    }
}

// ---------------------------------------------------------------------------
// 256x256 deep-pipelined GEMM (T2+T3+T4+T5): 512 thr / 8 waves (2Mx4N share of
// each 128x128 quadrant), BK=64, dyn-LDS 128KB = 2 bufs x 4 halves x 16KB.
// 4 phases/K-tile, quadrant order (A0B0)(A0B1)(A1B0)(A1B1); staging calendar:
// P1: Bh1,Ah1(kt+1)->buf^1 (dead since kt-1 end); P3: Ah0(kt+2)->buf (dead
// after P2); P4: Bh0(kt+2)->buf (dead after P3). Tile-end s_waitcnt vmcnt(4)
// keeps exactly {Ah0,Bh0}(kt+1) in flight across the barrier (T4).
// epi: 0=bf16; 5=f32+bias; 6=interleaved silu (g/u col pairs, rowsc).
__global__ __launch_bounds__(512) void gemm256(
    const bf16* __restrict__ A, const bf16* __restrict__ Bt,
    float* __restrict__ Cf, bf16* __restrict__ Cb,
    const float* __restrict__ bias, const float* __restrict__ rowsc,
    int M, int N, int K, int ldA, int ldB, int ldC, int limb3, int epi)
{
    extern __shared__ __align__(16) bf16 LDS[];
    const int tid = threadIdx.x;
    const int lane = tid & 63, wid = tid >> 6;
    const int l32 = lane & 31, lh2 = lane >> 5;
    const int wm2 = wid >> 2, wn4 = wid & 3;
    int lid = blockIdx.y * gridDim.x + blockIdx.x;
    {
        const int nwg = gridDim.x * gridDim.y;
        const int q = nwg >> 3, r = nwg & 7;
        const int xcd = lid & 7, idx = lid >> 3;
        lid = (xcd < r ? xcd * (q + 1) : r * (q + 1) + (xcd - r) * q) + idx;
    }
    const int m0 = (lid % gridDim.x) * 256, n0 = (lid / gridDim.x) * 256;
    const int NT = K / 64;

    int srow[2], sslot[2];
    #pragma unroll
    for (int i = 0; i < 2; i++) {
        const int c2 = tid + 512*i;
        srow[i]  = c2 >> 3;
        sslot[i] = ((c2 & 7) ^ (srow[i] & 7)) << 3;
    }

#define KMAP(kt, ka_, kb_) \
    int ka_ = (kt) * 64, kb_ = (kt) * 64; \
    if (limb3) { if (ka_ >= 4096) ka_ -= 4096; if (kb_ >= 2048) kb_ -= 2048; }

#define STAGE_HALF(op, h, kt, buf) do { \
    KMAP(kt, ka_, kb_); \
    const bf16* bas_ = (op) ? Bt : A; \
    const int gr0_ = ((op) ? n0 : m0) + (h)*128; \
    const int ld_ = (op) ? ldB : ldA; \
    const int ks_ = (op) ? kb_ : ka_; \
    bf16* dst_ = LDS + ((size_t)((buf)*4 + (op)*2 + (h))) * 8192; \
    _Pragma("unroll") \
    for (int i_ = 0; i_ < 2; i_++) \
        load_lds16(bas_ + (size_t)(gr0_ + srow[i_]) * ld_ + ks_ + sslot[i_], \
                   dst_ + (tid + 512*i_) * 8); \
} while (0)

    f32x16 acc00[2], acc01[2], acc10[2], acc11[2];
    #pragma unroll
    for (int m = 0; m < 2; m++)
        #pragma unroll
        for (int j = 0; j < 16; j++) {
            acc00[m][j] = 0.f; acc01[m][j] = 0.f;
            acc10[m][j] = 0.f; acc11[m][j] = 0.f;
        }

    // prologue: tile0 fully + Ah0,Bh0 of tile1; drain tile0, keep tile1 halves.
    STAGE_HALF(0, 0, 0, 0);
    STAGE_HALF(1, 0, 0, 0);
    STAGE_HALF(1, 1, 0, 0);
    STAGE_HALF(0, 1, 0, 0);
    if (NT > 1) { STAGE_HALF(0, 0, 1, 1); STAGE_HALF(1, 0, 1, 1); }
    asm volatile("s_waitcnt vmcnt(4)" ::: "memory");
    __builtin_amdgcn_s_barrier();
    asm volatile("" ::: "memory");

#define PHASE(QA, QB, ACC, STAGES) do { \
    const bf16* As_ = LDS + ((size_t)(c*4 + (QA))) * 8192; \
    const bf16* Bs_ = LDS + ((size_t)(c*4 + 2 + (QB))) * 8192; \
    const int rb_ = wn4*32 + l32; \
    bf16x8 a_[2][4], b_[4]; \
    _Pragma("unroll") \
    for (int kk = 0; kk < 4; kk++) { \
        _Pragma("unroll") \
        for (int m = 0; m < 2; m++) { \
            const int r_ = wm2*64 + m*32 + l32; \
            a_[m][kk] = *(const bf16x8*)&As_[r_*64 + ((((kk<<1)|lh2) ^ (r_&7)) << 3)]; \
        } \
        b_[kk] = *(const bf16x8*)&Bs_[rb_*64 + ((((kk<<1)|lh2) ^ (rb_&7)) << 3)]; \
    } \
    STAGES; \
    __builtin_amdgcn_s_barrier(); \
    asm volatile("" ::: "memory"); \
    __builtin_amdgcn_s_setprio(1); \
    _Pragma("unroll") \
    for (int kk = 0; kk < 4; kk++) { \
        ACC[0] = __builtin_amdgcn_mfma_f32_32x32x16_bf16(a_[0][kk], b_[kk], ACC[0], 0, 0, 0); \
        ACC[1] = __builtin_amdgcn_mfma_f32_32x32x16_bf16(a_[1][kk], b_[kk], ACC[1], 0, 0, 0); \
    } \
    __builtin_amdgcn_s_setprio(0); \
    __builtin_amdgcn_s_barrier(); \
    asm volatile("" ::: "memory"); \
} while (0)

    for (int kt = 0; kt < NT; kt++) {
        const int c = kt & 1;
        PHASE(0, 0, acc00, {
            if (kt + 1 < NT) { STAGE_HALF(1, 1, kt+1, c^1); STAGE_HALF(0, 1, kt+1, c^1); }
        });
        PHASE(0, 1, acc01, {});
        PHASE(1, 0, acc10, { if (kt + 2 < NT) STAGE_HALF(0, 0, kt+2, c); });
        PHASE(1, 1, acc11, { if (kt + 2 < NT) STAGE_HALF(1, 0, kt+2, c); });
        asm volatile("s_waitcnt vmcnt(4)" ::: "memory");
        __builtin_amdgcn_s_barrier();
        asm volatile("" ::: "memory");
    }

#define EPI(QA, QB, ACC) do { \
    _Pragma("unroll") \
    for (int m = 0; m < 2; m++) { \
        const int base_m = m0 + (QA)*128 + wm2*64 + m*32 + 4*lh2; \
        const int gcol = n0 + (QB)*128 + wn4*32 + l32; \
        _Pragma("unroll") \
        for (int reg = 0; reg < 16; reg++) { \
            const int grow = base_m + (reg & 3) + 8*(reg >> 2); \
            const float v = ACC[m][reg]; \
            if (epi == 6) { \
                const float pv = __shfl_xor(v, 1); \
                if (!(l32 & 1)) { \
                    const float g = v, u = pv; \
                    const float y = rowsc[grow] * g / (1.0f + __expf(-g)) * u; \
                    Cb[(size_t)grow * ldC + (gcol >> 1)] = f2b(y); \
                } \
            } else if (epi == 5) { \
                Cf[(size_t)grow * ldC + gcol] = v + bias[gcol]; \
            } else { \
                Cb[(size_t)grow * ldC + gcol] = f2b(v); \
            } \
        } \
    } \
} while (0)

    EPI(0, 0, acc00);
    EPI(0, 1, acc01);
    EPI(1, 0, acc10);
    EPI(1, 1, acc11);
#undef EPI
#undef PHASE
#undef STAGE_HALF
#undef KMAP
}

// ---------------------------------------------------------------------------
// 128^2 GEMM (m97-structure, BK=64, swizzled) — o-proj / shared-down.
// epi: 0=bf16 store; 4=f32 store at Cf + z*zCstride; 5=f32+bias.
__global__ __launch_bounds__(256) void gemm_bt(
    const bf16* __restrict__ A, const bf16* __restrict__ Bt,
    float* __restrict__ Cf, bf16* __restrict__ Cb, const float* __restrict__ bias,
    const float* __restrict__ rowsc,
    int M, int N, int K, int ldA, int ldB, int ldC, long zCstride, int limb3, int epi)
{
    __shared__ __align__(16) bf16 As[128 * 64];
    __shared__ __align__(16) bf16 Bs[128 * 64];
    const int tid = threadIdx.x;
    const int lane = tid & 63, wid = tid >> 6;
    const int l32 = lane & 31, lh2 = lane >> 5;
    const int wr = wid >> 1, wc = wid & 1;
    int lid = blockIdx.y * gridDim.x + blockIdx.x;
    {
        const int nwg = gridDim.x * gridDim.y;
        const int q = nwg >> 3, r = nwg & 7;
        const int xcd = lid & 7, idx = lid >> 3;
        lid = (xcd < r ? xcd * (q + 1) : r * (q + 1) + (xcd - r) * q) + idx;
    }
    const int m0 = (lid % gridDim.x) * 128, n0 = (lid / gridDim.x) * 128;
    const int koff = blockIdx.z * K;

    int srow[4], sslot[4];
    #pragma unroll
    for (int i = 0; i < 4; i++) {
        const int c = tid + 256*i;
        srow[i]  = c >> 3;
        sslot[i] = (((c & 7) ^ (srow[i] & 7)) << 3);
    }

    f32x16 acc[2][2];
    #pragma unroll
    for (int m = 0; m < 2; m++)
        #pragma unroll
        for (int n = 0; n < 2; n++)
            #pragma unroll
            for (int j = 0; j < 16; j++) acc[m][n][j] = 0.f;

    for (int k0 = 0; k0 < K; k0 += 64) {
        const int kcat = koff + k0;
        int ka = kcat, kb = kcat;
        if (limb3) {
            ka = (kcat >= 4096) ? kcat - 4096 : kcat;
            kb = (kcat >= 2048) ? kcat - 2048 : kcat;
        }
        __syncthreads();
        #pragma unroll
        for (int i = 0; i < 4; i++) {
            load_lds16(A  + (size_t)(m0 + srow[i]) * ldA + ka + sslot[i], As + (tid + 256*i) * 8);
            load_lds16(Bt + (size_t)(n0 + srow[i]) * ldB + kb + sslot[i], Bs + (tid + 256*i) * 8);
        }
        __syncthreads();
        bf16x8 a[2][4], b[2][4];
        #pragma unroll
        for (int m = 0; m < 2; m++) {
            const int r = wr*64 + m*32 + l32, rx = r & 7;
            #pragma unroll
            for (int kk = 0; kk < 4; kk++)
                a[m][kk] = *(const bf16x8*)&As[r*64 + ((((kk<<1)|lh2) ^ rx) << 3)];
        }
        #pragma unroll
        for (int n = 0; n < 2; n++) {
            const int r = wc*64 + n*32 + l32, rx = r & 7;
            #pragma unroll
            for (int kk = 0; kk < 4; kk++)
                b[n][kk] = *(const bf16x8*)&Bs[r*64 + ((((kk<<1)|lh2) ^ rx) << 3)];
        }
        #pragma unroll
        for (int kk = 0; kk < 4; kk++)
            #pragma unroll
            for (int m = 0; m < 2; m++)
                #pragma unroll
                for (int n = 0; n < 2; n++)
                    acc[m][n] = __builtin_amdgcn_mfma_f32_32x32x16_bf16(a[m][kk], b[n][kk], acc[m][n], 0, 0, 0);
    }

    float* Cz = Cf + (size_t)blockIdx.z * zCstride;
    #pragma unroll
    for (int m = 0; m < 2; m++) {
        const int base_m = m0 + wr*64 + m*32 + 4*lh2;
        #pragma unroll
        for (int n = 0; n < 2; n++) {
            const int gcol = n0 + wc*64 + n*32 + l32;
            #pragma unroll
            for (int reg = 0; reg < 16; reg++) {
                const int grow = base_m + (reg & 3) + 8*(reg >> 2);
                const size_t o = (size_t)grow * ldC + gcol;
                const float v = acc[m][n][reg];
                if (epi == 0)      Cb[o] = f2b(v);
                else if (epi == 4) Cz[o] = v;
                else               Cf[o] = v + bias[gcol];
            }
        }
    }
}

// ---------------------------------------------------------------------------
__global__ __launch_bounds__(256) void gemm_gu(
    const bf16* __restrict__ A, const bf16* __restrict__ BtAll,
    const int* __restrict__ offc, const int* __restrict__ perm,
    const float* __restrict__ scale, bf16* __restrict__ AB)
{
    const int e = blockIdx.z;
    const int off = offc[8 + e];
    const int padCnt = offc[9 + e] - off;
    const int m0 = blockIdx.x * 128;
    if (m0 >= padCnt) return;
    __shared__ __align__(16) bf16 As[128 * 64];
    __shared__ __align__(16) bf16 Bs[128 * 64];
    const int tid = threadIdx.x;
    const int lane = tid & 63, wid = tid >> 6;
    const int l32 = lane & 31, lh2 = lane >> 5;
    const int wr = wid >> 1, wc = wid & 1;
    const int n0 = blockIdx.y * 128;
    const bf16* Bt = BtAll + (size_t)e * 2816 * 2048;

    int srow[4], sslot[4], tok[4];
    #pragma unroll
    for (int i = 0; i < 4; i++) {
        const int c = tid + 256*i;
        srow[i]  = c >> 3;
        sslot[i] = (((c & 7) ^ (srow[i] & 7)) << 3);
        int t = perm[off + m0 + srow[i]];
        tok[i] = (t < 0) ? 0 : t;
    }

    f32x16 acc[2][2];
    #pragma unroll
    for (int m = 0; m < 2; m++)
        #pragma unroll
        for (int n = 0; n < 2; n++)
            #pragma unroll
            for (int j = 0; j < 16; j++) acc[m][n][j] = 0.f;

    for (int k0 = 0; k0 < 2048; k0 += 64) {
        __syncthreads();
        #pragma unroll
        for (int i = 0; i < 4; i++) {
            load_lds16(A  + (size_t)tok[i] * 2048 + k0 + sslot[i], As + (tid + 256*i) * 8);
            load_lds16(Bt + (size_t)(n0 + srow[i]) * 2048 + k0 + sslot[i], Bs + (tid + 256*i) * 8);
        }
        __syncthreads();
        bf16x8 a[2][4], b[2][4];
        #pragma unroll
        for (int m = 0; m < 2; m++) {
            const int r = wr*64 + m*32 + l32, rx = r & 7;
            #pragma unroll
            for (int kk = 0; kk < 4; kk++)
                a[m][kk] = *(const bf16x8*)&As[r*64 + ((((kk<<1)|lh2) ^ rx) << 3)];
        }
        #pragma unroll
        for (int n = 0; n < 2; n++) {
            const int r = wc*64 + n*32 + l32, rx = r & 7;
            #pragma unroll
            for (int kk = 0; kk < 4; kk++)
                b[n][kk] = *(const bf16x8*)&Bs[r*64 + ((((kk<<1)|lh2) ^ rx) << 3)];
        }
        #pragma unroll
        for (int kk = 0; kk < 4; kk++)
            #pragma unroll
            for (int m = 0; m < 2; m++)
                #pragma unroll
                for (int n = 0; n < 2; n++)
                    acc[m][n] = __builtin_amdgcn_mfma_f32_32x32x16_bf16(a[m][kk], b[n][kk], acc[m][n], 0, 0, 0);
    }

    #pragma unroll
    for (int m = 0; m < 2; m++) {
        const int base_m = m0 + wr*64 + m*32 + 4*lh2;
        #pragma unroll
        for (int n = 0; n < 2; n++) {
            const int gcol = n0 + wc*64 + n*32 + l32;
            #pragma unroll
            for (int reg = 0; reg < 16; reg++) {
                const int grow = base_m + (reg & 3) + 8*(reg >> 2);
                const float v = acc[m][n][reg];
                const float pv = __shfl_xor(v, 1);
                if (!(l32 & 1)) {
                    const float g = v, u = pv;
                    const float y = scale[off + grow] * g / (1.0f + __expf(-g)) * u;
                    AB[(size_t)(off + grow) * MOE_I + (gcol >> 1)] = f2b(y);
                }
            }
        }
    }
}

__global__ __launch_bounds__(256) void gemm_down(
    const bf16* __restrict__ A, const bf16* __restrict__ BtAll,
    const int* __restrict__ offc, bf16* __restrict__ Y)
{
    const int e = blockIdx.z;
    const int off = offc[8 + e];
    const int padCnt = offc[9 + e] - off;
    const int m0 = blockIdx.x * 128;
    if (m0 >= padCnt) return;
    __shared__ __align__(16) bf16 As[128 * 64];
    __shared__ __align__(16) bf16 Bs[128 * 64];
    const int tid = threadIdx.x;
    const int lane = tid & 63, wid = tid >> 6;
    const int l32 = lane & 31, lh2 = lane >> 5;
    const int wr = wid >> 1, wc = wid & 1;
    const int n0 = blockIdx.y * 128;
    const bf16* Bt = BtAll + (size_t)e * 2048 * 1408;

    int srow[4], sslot[4];
    #pragma unroll
    for (int i = 0; i < 4; i++) {
        const int c = tid + 256*i;
        srow[i]  = c >> 3;
        sslot[i] = (((c & 7) ^ (srow[i] & 7)) << 3);
    }

    f32x16 acc[2][2];
    #pragma unroll
    for (int m = 0; m < 2; m++)
        #pragma unroll
        for (int n = 0; n < 2; n++)
            #pragma unroll
            for (int j = 0; j < 16; j++) acc[m][n][j] = 0.f;

    for (int k0 = 0; k0 < 1408; k0 += 64) {
        __syncthreads();
        #pragma unroll
        for (int i = 0; i < 4; i++) {
            load_lds16(A  + (size_t)(off + m0 + srow[i]) * 1408 + k0 + sslot[i], As + (tid + 256*i) * 8);
            load_lds16(Bt + (size_t)(n0 + srow[i]) * 1408 + k0 + sslot[i], Bs + (tid + 256*i) * 8);
        }
        __syncthreads();
        bf16x8 a[2][4], b[2][4];
        #pragma unroll
        for (int m = 0; m < 2; m++) {
            const int r = wr*64 + m*32 + l32, rx = r & 7;
            #pragma unroll
            for (int kk = 0; kk < 4; kk++)
                a[m][kk] = *(const bf16x8*)&As[r*64 + ((((kk<<1)|lh2) ^ rx) << 3)];
        }
        #pragma unroll
        for (int n = 0; n < 2; n++) {
            const int r = wc*64 + n*32 + l32, rx = r & 7;
            #pragma unroll
            for (int kk = 0; kk < 4; kk++)
                b[n][kk] = *(const bf16x8*)&Bs[r*64 + ((((kk<<1)|lh2) ^ rx) << 3)];
        }
        #pragma unroll
        for (int kk = 0; kk < 4; kk++)
            #pragma unroll
            for (int m = 0; m < 2; m++)
                #pragma unroll
                for (int n = 0; n < 2; n++)
                    acc[m][n] = __builtin_amdgcn_mfma_f32_32x32x16_bf16(a[m][kk], b[n][kk], acc[m][n], 0, 0, 0);
    }

    #pragma unroll
    for (int m = 0; m < 2; m++) {
        const int base_m = m0 + wr*64 + m*32 + 4*lh2;
        #pragma unroll
        for (int n = 0; n < 2; n++) {
            const int gcol = n0 + wc*64 + n*32 + l32;
            #pragma unroll
            for (int reg = 0; reg < 16; reg++) {
                const int grow = base_m + (reg & 3) + 8*(reg >> 2);
                Y[(size_t)(off + grow) * 2048 + gcol] = f2b(acc[m][n][reg]);
            }
        }
    }
}

// ---------------------------------------------------------------------------
__global__ void rope_table_k(float2* __restrict__ cs)
{
    const int i = blockIdx.x * 256 + threadIdx.x;   // < 65536
    const int s = i >> 6, d = i & 63;
    const float fr = (float)s * powf(1.0e6f, -(float)d * (1.0f / 64.0f));
    float c, sn;
    sincosf(fr, &sn, &c);
    cs[i] = make_float2(c, sn);
}

// ---------------------------------------------------------------------------
__global__ __launch_bounds__(256) void transpose_v3_k(
    const float* __restrict__ qkv, bf16* __restrict__ vth, bf16* __restrict__ vtl)
{
    __shared__ float t[32][33];
    const int s0 = blockIdx.x * 32, d0 = blockIdx.y * 32;
    const int bh = blockIdx.z, b = bh >> 4, h = bh & 15;
    const int tx = threadIdx.x & 31, ty = threadIdx.x >> 5;
    const float* vb = qkv + ((size_t)b * SEQ) * 6144 + 4096 + h * HD;
    #pragma unroll
    for (int i = 0; i < 4; i++)
        t[ty + i*8][tx] = vb[(size_t)(s0 + ty + i*8) * 6144 + d0 + tx];
    __syncthreads();
    const size_t ob = ((size_t)bh * HD) * SEQ;
    #pragma unroll
    for (int i = 0; i < 4; i++) {
        float val = t[tx][ty + i*8];
        short hi, lo; split2(val, hi, lo);
        const size_t o = ob + (size_t)(d0 + ty + i*8) * SEQ + s0 + tx;
        vth[o] = __builtin_bit_cast(bf16, hi);
        vtl[o] = __builtin_bit_cast(bf16, lo);
    }
}

// ---------------------------------------------------------------------------
__global__ __launch_bounds__(256) void attn3_k(
    const float* __restrict__ qkv, const float2* __restrict__ ropecs,
    const bf16* __restrict__ vthg, const bf16* __restrict__ vtlg,
    bf16* __restrict__ ctx2)
{
    __shared__ __align__(16) bf16 SM[32768];   // 64 KB
    bf16* Ksh = SM;
    bf16* Ksl = SM + 8192;
    bf16* Vth = SM + 16384;
    bf16* Vtl = SM + 24576;
    bf16* Ph  = SM;
    bf16* Pl  = SM + 4096;

    const int tid = threadIdx.x, lane = tid & 63, wid = tid >> 6;
    const int l16 = lane & 15, lh = lane >> 4;
    const int bh = blockIdx.y, b = bh >> 4, h = bh & 15;
    const int qbase = blockIdx.x * 64;
    const int qw = qbase + wid * 16;
    const float* qp = qkv + ((size_t)b * SEQ) * 6144 + h * HD;
    const float* kp = qkv + ((size_t)b * SEQ) * 6144 + 2048 + h * HD;
    const bf16* vph = vthg + ((size_t)bh * HD) * SEQ;
    const bf16* vpl = vtlg + ((size_t)bh * HD) * SEQ;

    bf16x8 aqh[4], aql[4];
    {
        float qr[4][8];
        const int tok = qw + l16;
        #pragma unroll
        for (int c = 0; c < 4; c++) {
            const float* qrow = qp + (size_t)tok * 6144 + c*32 + lh*8;
            #pragma unroll
            for (int u = 0; u < 8; u++) qr[c][u] = qrow[u];
        }
        #pragma unroll
        for (int c = 0; c < 2; c++)
            #pragma unroll
            for (int u = 0; u < 8; u++) {
                const int d = c*32 + lh*8 + u;
                const float2 cs_ = ropecs[(tok << 6) | d];
                const float a = qr[c][u], bb = qr[c+2][u];
                qr[c][u]   = a * cs_.x - bb * cs_.y;
                qr[c+2][u] = bb * cs_.x + a * cs_.y;
            }
        #pragma unroll
        for (int c = 0; c < 4; c++)
            #pragma unroll
            for (int u = 0; u < 8; u++) {
                short hi, lo; split2(qr[c][u], hi, lo);
                aqh[c][u] = hi; aql[c][u] = lo;
            }
    }

    f32x4 o[8];
    #pragma unroll
    for (int n = 0; n < 8; n++) o[n] = (f32x4){0.f, 0.f, 0.f, 0.f};
    float mj[4], lj[4];
    #pragma unroll
    for (int j = 0; j < 4; j++) { mj[j] = -1e30f; lj[j] = 0.f; }

    const int kr = tid >> 2;
    const int q16 = tid & 3;
    const int krx = kr & 15;
    const int kt_end = blockIdx.x + 1;
    for (int kt = 0; kt < kt_end; ++kt) {
        const int kv0 = kt * 64;
        __syncthreads();
        {
            const int tokk = kv0 + kr;
            const float* krow = kp + (size_t)tokk * 6144;
            float4 A4[4], B4[4];
            #pragma unroll
            for (int u = 0; u < 4; u++) {
                A4[u] = *(const float4*)(krow + q16*16 + u*4);
                B4[u] = *(const float4*)(krow + 64 + q16*16 + u*4);
            }
            #pragma unroll
            for (int u = 0; u < 4; u++) {
                #pragma unroll
                for (int j = 0; j < 4; j++) {
                    const int d = q16*16 + u*4 + j;
                    const float2 cs_ = ropecs[(tokk << 6) | d];
                    float* pa = ((float*)&A4[u]) + j;
                    float* pb = ((float*)&B4[u]) + j;
                    const float a = *pa, bb = *pb;
                    *pa = a * cs_.x - bb * cs_.y;
                    *pb = bb * cs_.x + a * cs_.y;
                }
                bf16x4 h4, l4, h4b, l4b;
                #pragma unroll
                for (int j = 0; j < 4; j++) {
                    short hi, lo;
                    split2(((float*)&A4[u])[j], hi, lo); h4[j] = hi; l4[j] = lo;
                    split2(((float*)&B4[u])[j], hi, lo); h4b[j] = hi; l4b[j] = lo;
                }
                const int colA = q16*16 + u*4;
                const int sA = ((colA >> 3) ^ krx);
                const int dstA = kr*128 + (sA << 3) + ((u & 1) * 4);
                *(bf16x4*)&Ksh[dstA] = h4;
                *(bf16x4*)&Ksl[dstA] = l4;
                const int colB = 64 + colA;
                const int sB = ((colB >> 3) ^ krx);
                const int dstB = kr*128 + (sB << 3) + ((u & 1) * 4);
                *(bf16x4*)&Ksh[dstB] = h4b;
                *(bf16x4*)&Ksl[dstB] = l4b;
            }
        }
        #pragma unroll
        for (int i = 0; i < 4; i++) {
            const int c = tid + 256*i;
            const int row = c >> 3, sl = (c & 7) ^ (row & 7);
            load_lds16(vph + (size_t)row * SEQ + kv0 + (sl << 3), Vth + c*8);
            load_lds16(vpl + (size_t)row * SEQ + kv0 + (sl << 3), Vtl + c*8);
        }
        __syncthreads();

        f32x4 sg[4];
        #pragma unroll
        for (int g = 0; g < 4; g++) sg[g] = (f32x4){0.f,0.f,0.f,0.f};
        __builtin_amdgcn_s_setprio(1);
        #pragma unroll
        for (int c = 0; c < 4; c++) {
            #pragma unroll
            for (int g = 0; g < 4; g++) {
                const int row = l16 + g*16;
                const int sl = (((c*4 + lh) ^ (row & 15)) << 3);
                bf16x8 bkh = *(const bf16x8*)&Ksh[row*128 + sl];
                bf16x8 bkl = *(const bf16x8*)&Ksl[row*128 + sl];
                sg[g] = __builtin_amdgcn_mfma_f32_16x16x32_bf16(aqh[c], bkh, sg[g], 0, 0, 0);
                sg[g] = __builtin_amdgcn_mfma_f32_16x16x32_bf16(aql[c], bkh, sg[g], 0, 0, 0);
                sg[g] = __builtin_amdgcn_mfma_f32_16x16x32_bf16(aqh[c], bkl, sg[g], 0, 0, 0);
            }
        }
        __builtin_amdgcn_s_setprio(0);
        __syncthreads();

        const float scale = 0.08838834764831845f;
        #pragma unroll
        for (int j = 0; j < 4; j++) {
            const int qrow = qw + lh*4 + j;
            float sv[4];
            #pragma unroll
            for (int g = 0; g < 4; g++) {
                sv[g] = sg[g][j] * scale;
                if (kv0 + l16 + g*16 > qrow) sv[g] = -1e30f;
            }
            float mx = fmaxf(fmaxf(sv[0], sv[1]), fmaxf(sv[2], sv[3]));
            #pragma unroll
            for (int off = 1; off < 16; off <<= 1) mx = fmaxf(mx, __shfl_xor(mx, off, 16));
            const float nm = fmaxf(mj[j], mx);
            const float al = __expf(mj[j] - nm);
            float pg[4], rs = 0.f;
            #pragma unroll
            for (int g = 0; g < 4; g++) { pg[g] = __expf(sv[g] - nm); rs += pg[g]; }
            #pragma unroll
            for (int off = 1; off < 16; off <<= 1) rs += __shfl_xor(rs, off, 16);
            lj[j] = lj[j] * al + rs;
            mj[j] = nm;
            #pragma unroll
            for (int n = 0; n < 8; n++) o[n][j] *= al;
            const int prow = lh*4 + j;
            #pragma unroll
            for (int g = 0; g < 4; g++) {
                short hi, lo; split2(pg[g], hi, lo);
                const int col = l16 + g*16;
                const int addr = wid*1024 + prow*64 + ((((col >> 3) ^ (prow & 7)) << 3)) + (col & 7);
                Ph[addr] = __builtin_bit_cast(bf16, hi);
                Pl[addr] = __builtin_bit_cast(bf16, lo);
            }
        }
        __builtin_amdgcn_s_setprio(1);
        #pragma unroll
        for (int ks = 0; ks < 2; ks++) {
            const int psl = (((ks*4 + lh) ^ (l16 & 7)) << 3);
            bf16x8 aph = *(const bf16x8*)&Ph[wid*1024 + l16*64 + psl];
            bf16x8 apl = *(const bf16x8*)&Pl[wid*1024 + l16*64 + psl];
            #pragma unroll
            for (int n = 0; n < 8; n++) {
                const int row = n*16 + l16;
                const int vsl = (((ks*4 + lh) ^ (row & 7)) << 3);
                bf16x8 bvh = *(const bf16x8*)&Vth[row*64 + vsl];
                bf16x8 bvl = *(const bf16x8*)&Vtl[row*64 + vsl];
                o[n] = __builtin_amdgcn_mfma_f32_16x16x32_bf16(aph, bvh, o[n], 0, 0, 0);
                o[n] = __builtin_amdgcn_mfma_f32_16x16x32_bf16(apl, bvh, o[n], 0, 0, 0);
                o[n] = __builtin_amdgcn_mfma_f32_16x16x32_bf16(aph, bvl, o[n], 0, 0, 0);
            }
        }
        __builtin_amdgcn_s_setprio(0);
    }

    float inv[4];
    #pragma unroll
    for (int j = 0; j < 4; j++) inv[j] = 1.0f / lj[j];
    #pragma unroll
    for (int n = 0; n < 8; n++)
        #pragma unroll
        for (int j = 0; j < 4; j++) {
            const float v = o[n][j] * inv[j];
            short hi, lo; split2(v, hi, lo);
            const size_t base = ((size_t)b * SEQ + (qw + lh*4 + j)) * 4096 + h * HD + n*16 + l16;
            ctx2[base]        = __builtin_bit_cast(bf16, hi);
            ctx2[base + 2048] = __builtin_bit_cast(bf16, lo);
        }
}

// ---------------------------------------------------------------------------
__global__ __launch_bounds__(256) void combine_rms_router_k(
    const float* __restrict__ x, const float* __restrict__ xp,
    const float* __restrict__ wln, const float* __restrict__ wr,
    const float* __restrict__ weg,
    float* __restrict__ x1, bf16* __restrict__ h2,
    float* __restrict__ comb, float* __restrict__ sigeg)
{
    const int row = blockIdx.x, tid = threadIdx.x;
    const size_t rb = (size_t)row * HIDDEN;
    const long zs = (long)TOKENS * HIDDEN;
    __shared__ float ps[4];
    __shared__ float pacc[4][9];
    float4 v[2];
    #pragma unroll
    for (int u = 0; u < 2; u++) {
        const int i = tid + u * 256;
        float4 a  = ((const float4*)(x + rb))[i];
        float4 p0 = ((const float4*)(xp + rb))[i];
        float4 p1 = ((const float4*)(xp + zs + rb))[i];
        float4 p2 = ((const float4*)(xp + 2*zs + rb))[i];
        v[u].x = a.x + p0.x + p1.x + p2.x;
        v[u].y = a.y + p0.y + p1.y + p2.y;
        v[u].z = a.z + p0.z + p1.z + p2.z;
        v[u].w = a.w + p0.w + p1.w + p2.w;
        ((float4*)(x1 + rb))[i] = v[u];
    }
    float ss = v[0].x*v[0].x + v[0].y*v[0].y + v[0].z*v[0].z + v[0].w*v[0].w
             + v[1].x*v[1].x + v[1].y*v[1].y + v[1].z*v[1].z + v[1].w*v[1].w;
    #pragma unroll
    for (int off = 1; off < 64; off <<= 1) ss += __shfl_xor(ss, off);
    if ((tid & 63) == 0) ps[tid >> 6] = ss;
    __syncthreads();
    const float tot = ps[0] + ps[1] + ps[2] + ps[3];
    const float r = rsqrtf(tot * (1.0f / HIDDEN) + 1e-6f);

    float acc[9];
    #pragma unroll
    for (int e = 0; e < 9; e++) acc[e] = 0.f;
    #pragma unroll
    for (int u = 0; u < 2; u++) {
        const int i = (tid + u * 256) * 4;
        const float vv[4] = {v[u].x, v[u].y, v[u].z, v[u].w};
        #pragma unroll
        for (int q = 0; q < 4; q++) {
            const float hv = vv[q] * r * wln[i + q];
            h2[rb + i + q] = f2b(hv);
            const float* wrow = wr + (size_t)(i + q) * 8;
            #pragma unroll
            for (int e = 0; e < 8; e++) acc[e] += hv * wrow[e];
            acc[8] += hv * weg[i + q];
        }
    }
    #pragma unroll
    for (int e = 0; e < 9; e++)
        #pragma unroll
        for (int off = 1; off < 64; off <<= 1) acc[e] += __shfl_xor(acc[e], off);
    if ((tid & 63) == 0)
        #pragma unroll
        for (int e = 0; e < 9; e++) pacc[tid >> 6][e] = acc[e];
    __syncthreads();
    if (tid == 0) {
        float lg[9];
        #pragma unroll
        for (int e = 0; e < 9; e++) lg[e] = pacc[0][e] + pacc[1][e] + pacc[2][e] + pacc[3][e];
        float mx = lg[0];
        #pragma unroll
        for (int e = 1; e < 8; e++) mx = fmaxf(mx, lg[e]);
        float p[8], s = 0.f;
        #pragma unroll
        for (int e = 0; e < 8; e++) { p[e] = expf(lg[e] - mx); s += p[e]; }
        const float invs = 1.0f / s;
        #pragma unroll
        for (int e = 0; e < 8; e++) p[e] *= invs;
        int i1 = 0;
        #pragma unroll
        for (int e = 1; e < 8; e++) if (p[e] > p[i1]) i1 = e;
        int i2 = (i1 == 0) ? 1 : 0;
        #pragma unroll
        for (int e = 0; e < 8; e++) if (e != i1 && p[e] > p[i2]) i2 = e;
        #pragma unroll
        for (int e = 0; e < 8; e++)
            comb[(size_t)row * 8 + e] = (e == i1 || e == i2) ? p[e] : 0.f;
        sigeg[row] = 1.0f / (1.0f + expf(-lg[8]));
    }
}

// ---------------------------------------------------------------------------
__global__ __launch_bounds__(256) void count_fill_k(
    const float* __restrict__ comb, int* __restrict__ offc, int* __restrict__ perm,
    float* __restrict__ scale, int* __restrict__ inv)
{
    __shared__ int cnt[8], off[9], fil[8];
    const int tid = threadIdx.x;
    if (tid < 8) { cnt[tid] = 0; fil[tid] = 0; }
    __syncthreads();
    for (int t = tid; t < TOKENS; t += 256)
        #pragma unroll
        for (int e = 0; e < 8; e++)
            if (comb[(size_t)t * 8 + e] > 0.f) atomicAdd(&cnt[e], 1);
    __syncthreads();
    if (tid == 0) {
        off[0] = 0;
        for (int e = 0; e < 8; e++) off[e+1] = off[e] + ((cnt[e] + 127) & ~127);
    }
    __syncthreads();
    for (int i = tid; i < MAXROWS; i += 256) { perm[i] = -1; scale[i] = 0.f; }
    __syncthreads();
    for (int t = tid; t < TOKENS; t += 256) {
        int j = 0;
        #pragma unroll
        for (int e = 0; e < 8; e++) {
            const float c = comb[(size_t)t * 8 + e];
            if (c > 0.f) {
                int s = atomicAdd(&fil[e], 1);
                int slot = off[e] + s;
                perm[slot] = t;
                scale[slot] = c;
                inv[t * 2 + j] = slot;
                j++;
            }
        }
    }
    __syncthreads();
    if (tid < 9) offc[8 + tid] = off[tid];
}

// ---------------------------------------------------------------------------
__global__ void final_k(const float* __restrict__ x1, const bf16* __restrict__ y,
                        const int* __restrict__ inv, const float* __restrict__ ysh,
                        float* __restrict__ out)
{
    const int i = blockIdx.x * 256 + threadIdx.x;
    const int t = i >> 9;
    const int col = (i & 511) * 4;
    const int s0 = inv[t*2], s1 = inv[t*2 + 1];
    const long zs = (long)TOKENS * HIDDEN;
    float4 a  = ((const float4*)x1)[i];
    float4 h0 = ((const float4*)ysh)[i];
    float4 h1 = ((const float4*)(ysh + zs))[i];
    const bf16* y0 = y + (size_t)s0 * 2048 + col;
    const bf16* y1 = y + (size_t)s1 * 2048 + col;
    float4 r;
    r.x = a.x + h0.x + h1.x + b2f(y0[0]) + b2f(y1[0]);
    r.y = a.y + h0.y + h1.y + b2f(y0[1]) + b2f(y1[1]);
    r.z = a.z + h0.z + h1.z + b2f(y0[2]) + b2f(y1[2]);
    r.w = a.w + h0.w + h1.w + b2f(y0[3]) + b2f(y1[3]);
    ((float4*)out)[i] = r;
}

// ---------------------------------------------------------------------------
extern "C" void kernel_launch(void* const* d_in, const int* in_sizes, int n_in,
                              void* d_out, int out_size, void* d_ws, size_t ws_size,
                              hipStream_t stream)
{
    const float* x     = (const float*)d_in[0];
    const float* w_ln1 = (const float*)d_in[1];
    const float* wq    = (const float*)d_in[2];
    const float* bq    = (const float*)d_in[3];
    const float* wk    = (const float*)d_in[4];
    const float* bk    = (const float*)d_in[5];
    const float* wv    = (const float*)d_in[6];
    const float* bv    = (const float*)d_in[7];
    const float* wo    = (const float*)d_in[8];
    const float* w_ln2 = (const float*)d_in[9];
    const float* w_rt  = (const float*)d_in[10];
    const float* w_ge  = (const float*)d_in[11];
    const float* w_ue  = (const float*)d_in[12];
    const float* w_de  = (const float*)d_in[13];
    const float* w_sg  = (const float*)d_in[14];
    const float* w_su  = (const float*)d_in[15];
    const float* w_sd  = (const float*)d_in[16];
    const float* w_eg  = (const float*)d_in[17];
    float* out = (float*)d_out;
    (void)in_sizes; (void)n_in; (void)out_size; (void)ws_size;

    char* ws = (char*)d_ws;
    float* x1    = (float*)(ws + 0);
    bf16*  h2    = (bf16*)(ws + 16777216);
    float* comb  = (float*)(ws + 25165824);
    float* seg   = (float*)(ws + 25231360);
    int*   offc  = (int*)(ws + 25239552);
    float* scale = (float*)(ws + 25243648);
    int*   perm  = (int*)(ws + 25276416);
    int*   inv   = (int*)(ws + 25297920);
    float* bqkv  = (float*)(ws + 25314304);
    float2* ropecs = (float2*)(ws + 25338880);
    const size_t S = 25863168;
    // phase A
    bf16*  hcat  = (bf16*)(ws + S);
    bf16*  wtqkv = (bf16*)(ws + S + 16777216);
    float* qkvf  = (float*)(ws + S + 67108864);
    bf16*  wt3o  = (bf16*)(ws + S + 117440512);
    bf16*  vth   = (bf16*)(ws + S);
    bf16*  vtl   = (bf16*)(ws + S + 8388608);
    bf16*  ctx2  = (bf16*)(ws + S + 16777216);
    float* xp    = (float*)(ws + S + 50331648);
    // phase B
    bf16*  wtgu  = (bf16*)(ws + S);
    bf16*  ab    = (bf16*)(ws + S + 92274688);
    bf16*  wtd   = (bf16*)(ws + S);
    bf16*  ymoe  = (bf16*)(ws + S + 46137344);
    // phase C
    bf16*  wtshgu = (bf16*)(ws + S);
    bf16*  ash    = (bf16*)(ws + S + 67108864);
    bf16*  wtshd  = (bf16*)(ws + S);
    float* ysh    = (float*)(ws + S + 90177536);

    // 1) RMSNorm1; bias concat; rope table
    rmsnorm3_k<<<TOKENS, 256, 0, stream>>>(x, w_ln1, hcat);
    (void)hipMemcpyAsync(bqkv,        bq, 8192, hipMemcpyDeviceToDevice, stream);
    (void)hipMemcpyAsync(bqkv + 2048, bk, 8192, hipMemcpyDeviceToDevice, stream);
    (void)hipMemcpyAsync(bqkv + 4096, bv, 8192, hipMemcpyDeviceToDevice, stream);
    rope_table_k<<<256, 256, 0, stream>>>(ropecs);

    // 2) QKVO transposes; fused QKV GEMM (256^2 deep-pipelined)
    transpose_qkvo_k<<<dim3(32, 32, 4), 256, 0, stream>>>(wq, wk, wv, wo, wtqkv, wt3o);
    gemm256<<<dim3(8, 24), 512, 131072, stream>>>(hcat, wtqkv, qkvf, nullptr, bqkv, nullptr,
                                                  TOKENS, 6144, K3, 4096, 4096, 6144, 1, 5);

    // 3) V transpose/split + attention (rope fused)
    transpose_v3_k<<<dim3(32, 4, 32), 256, 0, stream>>>(qkvf, vth, vtl);
    attn3_k<<<dim3(16, 32), 256, 0, stream>>>(qkvf, ropecs, vth, vtl, ctx2);

    // 4) O-proj (128^2, split-K z=3) + fused combine/rms/router + lists
    gemm_bt<<<dim3(16, 16, 3), 256, 0, stream>>>(ctx2, wt3o, xp, nullptr, nullptr, nullptr,
                                                 TOKENS, HIDDEN, 2048, 4096, 4096, 2048,
                                                 (long)TOKENS * HIDDEN, 1, 4);
    combine_rms_router_k<<<TOKENS, 256, 0, stream>>>(x, xp, w_ln2, w_rt, w_eg,
                                                     x1, h2, comb, seg);
    count_fill_k<<<1, 256, 0, stream>>>(comb, offc, perm, scale, inv);

    // 5) Sparse MoE (interleaved g/u; silu fused)
    transpose_moegu_k<<<dim3(22, 32, 16), 256, 0, stream>>>(w_ge, w_ue, wtgu);
    gemm_gu<<<dim3(MAXROWS/128, 22, 8), 256, 0, stream>>>(h2, wtgu, offc, perm, scale, ab);
    transpose64_k<<<dim3(32, 22, 8), 256, 0, stream>>>(w_de, wtd, MOE_I, HIDDEN,
                                                       (long)MOE_I*HIDDEN, (long)HIDDEN*MOE_I);
    gemm_down<<<dim3(MAXROWS/128, 16, 8), 256, 0, stream>>>(ab, wtd, offc, ymoe);

    // 6) Shared expert: gate|up via 256^2 pipelined GEMM (epi6 silu+seg)
    transpose_shgu_k<<<dim3(88, 32, 2), 256, 0, stream>>>(w_sg, w_su, wtshgu);
    gemm256<<<dim3(8, 44), 512, 131072, stream>>>(h2, wtshgu, nullptr, ash, nullptr, seg,
                                                  TOKENS, 2*SH_I, HIDDEN, HIDDEN, HIDDEN, SH_I, 0, 6);
    transpose64_k<<<dim3(32, 88, 1), 256, 0, stream>>>(w_sd, wtshd, SH_I, HIDDEN, 0, 0);
    gemm_bt<<<dim3(16, 16, 2), 256, 0, stream>>>(ash, wtshd, ysh, nullptr, nullptr, nullptr,
                                                 TOKENS, HIDDEN, SH_I/2, SH_I, SH_I, 2048,
                                                 (long)TOKENS * HIDDEN, 0, 4);

    // 7) Final gather-sum
    final_k<<<(TOKENS * HIDDEN) / 1024, 256, 0, stream>>>(x1, ymoe, inv, ysh, out);
}

// Round 12
// 967.959 us; speedup vs baseline: 1.1378x; 1.1378x over previous
//
#include <hip/hip_runtime.h>
#include <hip/hip_bf16.h>
#include <math.h>

#define TOKENS 2048
#define HIDDEN 2048
#define NH 16
#define HD 128
#define SEQ 1024
#define MOE_I 1408
#define SH_I 5632
#define K3 6144
#define MAXROWS 5120

typedef __hip_bfloat16 bf16;
typedef short bf16x8 __attribute__((ext_vector_type(8)));
typedef short bf16x4 __attribute__((ext_vector_type(4)));
typedef float f32x4 __attribute__((ext_vector_type(4)));
typedef float f32x16 __attribute__((ext_vector_type(16)));

__device__ __forceinline__ float b2f(bf16 x) { return __bfloat162float(x); }
__device__ __forceinline__ bf16 f2b(float x) { return __float2bfloat16(x); }
__device__ __forceinline__ void split2(float v, short& hi, short& lo) {
    bf16 h = f2b(v);
    bf16 l = f2b(v - b2f(h));
    hi = __builtin_bit_cast(short, h); lo = __builtin_bit_cast(short, lo = __builtin_bit_cast(short, l), l);
}

__device__ __forceinline__ void load_lds16(const void* g, void* l) {
    __builtin_amdgcn_global_load_lds(
        (const __attribute__((address_space(1))) unsigned int*)g,
        (__attribute__((address_space(3))) unsigned int*)l, 16, 0, 0);
}

// ---------------------------------------------------------------------------
__global__ __launch_bounds__(256) void rmsnorm3_k(
    const float* __restrict__ x, const float* __restrict__ w, bf16* __restrict__ out)
{
    const int row = blockIdx.x, tid = threadIdx.x;
    const float4* xr = (const float4*)(x + (size_t)row * HIDDEN);
    float4 v1 = xr[tid], v2 = xr[tid + 256];
    float ss = v1.x*v1.x + v1.y*v1.y + v1.z*v1.z + v1.w*v1.w
             + v2.x*v2.x + v2.y*v2.y + v2.z*v2.z + v2.w*v2.w;
    #pragma unroll
    for (int off = 1; off < 64; off <<= 1) ss += __shfl_xor(ss, off);
    __shared__ float ps[4];
    if ((tid & 63) == 0) ps[tid >> 6] = ss;
    __syncthreads();
    float tot = ps[0] + ps[1] + ps[2] + ps[3];
    float r = rsqrtf(tot * (1.0f / HIDDEN) + 1e-6f);
    bf16* o = out + (size_t)row * 4096;
    float vv[8] = {v1.x, v1.y, v1.z, v1.w, v2.x, v2.y, v2.z, v2.w};
    int idx[8]  = {tid*4, tid*4+1, tid*4+2, tid*4+3,
                   1024+tid*4, 1024+tid*4+1, 1024+tid*4+2, 1024+tid*4+3};
    #pragma unroll
    for (int u = 0; u < 8; u++) {
        bf16 h = f2b(vv[u] * r * w[idx[u]]);
        bf16 l = f2b(vv[u] * r * w[idx[u]] - b2f(h));
        o[idx[u]]        = h;
        o[2048 + idx[u]] = l;
    }
}

// ---------------------------------------------------------------------------
// Generic plain transpose (used for w_de, w_sd)
__global__ __launch_bounds__(256) void transpose_wz(
    const float* __restrict__ W, bf16* __restrict__ Wt, int K, int N,
    int nOff, long zsrc, long zdst)
{
    __shared__ float t[32][33];
    W  += (size_t)blockIdx.z * zsrc;
    Wt += (size_t)blockIdx.z * zdst;
    const int n0 = blockIdx.x * 32, k0 = blockIdx.y * 32;
    const int tx = threadIdx.x & 31, ty = threadIdx.x >> 5;
    #pragma unroll
    for (int i = 0; i < 4; i++)
        t[ty + i*8][tx] = W[(size_t)(k0 + ty + i*8) * N + n0 + tx];
    __syncthreads();
    #pragma unroll
    for (int i = 0; i < 4; i++)
        Wt[(size_t)(nOff + n0 + ty + i*8) * K + k0 + tx] = f2b(t[tx][ty + i*8]);
}

// Fused QKVO split-transpose: z=0..2 -> wtqkv rows z*2048.., z=3 -> wt3o.
__global__ __launch_bounds__(256) void transpose_qkvo_k(
    const float* __restrict__ wq, const float* __restrict__ wk,
    const float* __restrict__ wv, const float* __restrict__ wo,
    bf16* __restrict__ wtqkv, bf16* __restrict__ wt3o)
{
    const int z = blockIdx.z;
    const float* W = (z == 0) ? wq : (z == 1) ? wk : (z == 2) ? wv : wo;
    bf16* Wt2 = (z < 3) ? wtqkv : wt3o;
    const int nOff = (z < 3) ? z * 2048 : 0;
    __shared__ float t[32][33];
    const int n0 = blockIdx.x * 32, k0 = blockIdx.y * 32;
    const int tx = threadIdx.x & 31, ty = threadIdx.x >> 5;
    #pragma unroll
    for (int i = 0; i < 4; i++)
        t[ty + i*8][tx] = W[(size_t)(k0 + ty + i*8) * 2048 + n0 + tx];
    __syncthreads();
    #pragma unroll
    for (int i = 0; i < 4; i++) {
        float v = t[tx][ty + i*8];
        bf16 h = f2b(v);
        bf16 l = f2b(v - b2f(h));
        bf16* o = Wt2 + (size_t)(nOff + n0 + ty + i*8) * 4096 + k0 + tx;
        o[0]    = h;
        o[2048] = l;
    }
}

// Fused MoE gate|up transpose: z<8 -> gate expert z, z>=8 -> up expert z-8.
__global__ __launch_bounds__(256) void transpose_moegu_k(
    const float* __restrict__ ge, const float* __restrict__ ue, bf16* __restrict__ wtgu)
{
    const int z = blockIdx.z, e = z & 7;
    const float* W = ((z < 8) ? ge : ue) + (size_t)e * HIDDEN * MOE_I;
    bf16* Wt = wtgu + (size_t)e * 2816 * HIDDEN;
    const int nOff = (z < 8) ? 0 : MOE_I;
    __shared__ float t[32][33];
    const int n0 = blockIdx.x * 32, k0 = blockIdx.y * 32;
    const int tx = threadIdx.x & 31, ty = threadIdx.x >> 5;
    #pragma unroll
    for (int i = 0; i < 4; i++)
        t[ty + i*8][tx] = W[(size_t)(k0 + ty + i*8) * MOE_I + n0 + tx];
    __syncthreads();
    #pragma unroll
    for (int i = 0; i < 4; i++)
        Wt[(size_t)(nOff + n0 + ty + i*8) * HIDDEN + k0 + tx] = f2b(t[tx][ty + i*8]);
}

// Fused shared gate|up transpose: z=0 gate, z=1 up.
__global__ __launch_bounds__(256) void transpose_shgu_k(
    const float* __restrict__ sg, const float* __restrict__ su, bf16* __restrict__ dst)
{
    const int z = blockIdx.z;
    const float* W = z ? su : sg;
    const int nOff = z * SH_I;
    __shared__ float t[32][33];
    const int n0 = blockIdx.x * 32, k0 = blockIdx.y * 32;
    const int tx = threadIdx.x & 31, ty = threadIdx.x >> 5;
    #pragma unroll
    for (int i = 0; i < 4; i++)
        t[ty + i*8][tx] = W[(size_t)(k0 + ty + i*8) * SH_I + n0 + tx];
    __syncthreads();
    #pragma unroll
    for (int i = 0; i < 4; i++)
        dst[(size_t)(nOff + n0 + ty + i*8) * HIDDEN + k0 + tx] = f2b(t[tx][ty + i*8]);
}

// ---------------------------------------------------------------------------
// GEMM: 128x128x64 tile, 32x32x16 MFMA, XOR-swizzled LDS, XCD swizzle.
// epi: 0 = bf16 store; 4 = f32 store at Cf + z*zCstride; 5 = f32 + bias store.
__global__ __launch_bounds__(256) void gemm_bt(
    const bf16* __restrict__ A, const bf16* __restrict__ Bt,
    float* __restrict__ Cf, bf16* __restrict__ Cb, const float* __restrict__ bias,
    int M, int N, int K, int ldA, int ldB, int ldC, long zCstride, int limb3, int epi)
{
    __shared__ __align__(16) bf16 As[128 * 64];
    __shared__ __align__(16) bf16 Bs[128 * 64];
    const int tid = threadIdx.x;
    const int lane = tid & 63, wid = tid >> 6;
    const int l32 = lane & 31, lh2 = lane >> 5;
    const int wr = wid >> 1, wc = wid & 1;
    int lid = blockIdx.y * gridDim.x + blockIdx.x;
    {
        const int nwg = gridDim.x * gridDim.y;
        const int q = nwg >> 3, r = nwg & 7;
        const int xcd = lid & 7, idx = lid >> 3;
        lid = (xcd < r ? xcd * (q + 1) : r * (q + 1) + (xcd - r) * q) + idx;
    }
    const int m0 = (lid % gridDim.x) * 128, n0 = (lid / gridDim.x) * 128;
    const int koff = blockIdx.z * K;

    int srow[4], sslot[4];
    #pragma unroll
    for (int i = 0; i < 4; i++) {
        const int c = tid + 256*i;
        srow[i]  = c >> 3;
        sslot[i] = (((c & 7) ^ (srow[i] & 7)) << 3);
    }

    f32x16 acc[2][2];
    #pragma unroll
    for (int m = 0; m < 2; m++)
        #pragma unroll
        for (int n = 0; n < 2; n++)
            #pragma unroll
            for (int j = 0; j < 16; j++) acc[m][n][j] = 0.f;

    for (int k0 = 0; k0 < K; k0 += 64) {
        const int kcat = koff + k0;
        int ka = kcat, kb = kcat;
        if (limb3) {
            ka = (kcat >= 4096) ? kcat - 4096 : kcat;
            kb = (kcat >= 2048) ? kcat - 2048 : kcat;
        }
        __syncthreads();
        #pragma unroll
        for (int i = 0; i < 4; i++) {
            load_lds16(A  + (size_t)(m0 + srow[i]) * ldA + ka + sslot[i], As + (tid + 256*i) * 8);
            load_lds16(Bt + (size_t)(n0 + srow[i]) * ldB + kb + sslot[i], Bs + (tid + 256*i) * 8);
        }
        __syncthreads();
        bf16x8 a[2][4], b[2][4];
        #pragma unroll
        for (int m = 0; m < 2; m++) {
            const int r = wr*64 + m*32 + l32, rx = r & 7;
            #pragma unroll
            for (int kk = 0; kk < 4; kk++)
                a[m][kk] = *(const bf16x8*)&As[r*64 + ((((kk<<1)|lh2) ^ rx) << 3)];
        }
        #pragma unroll
        for (int n = 0; n < 2; n++) {
            const int r = wc*64 + n*32 + l32, rx = r & 7;
            #pragma unroll
            for (int kk = 0; kk < 4; kk++)
                b[n][kk] = *(const bf16x8*)&Bs[r*64 + ((((kk<<1)|lh2) ^ rx) << 3)];
        }
        #pragma unroll
        for (int kk = 0; kk < 4; kk++)
            #pragma unroll
            for (int m = 0; m < 2; m++)
                #pragma unroll
                for (int n = 0; n < 2; n++)
                    acc[m][n] = __builtin_amdgcn_mfma_f32_32x32x16_bf16(a[m][kk], b[n][kk], acc[m][n], 0, 0, 0);
    }

    float* Cz = Cf + (size_t)blockIdx.z * zCstride;
    #pragma unroll
    for (int m = 0; m < 2; m++) {
        const int base_m = m0 + wr*64 + m*32 + 4*lh2;
        #pragma unroll
        for (int n = 0; n < 2; n++) {
            const int gcol = n0 + wc*64 + n*32 + l32;
            #pragma unroll
            for (int reg = 0; reg < 16; reg++) {
                const int grow = base_m + (reg & 3) + 8*(reg >> 2);
                const size_t o = (size_t)grow * ldC + gcol;
                const float v = acc[m][n][reg];
                if (epi == 0)      Cb[o] = f2b(v);
                else if (epi == 4) Cz[o] = v;
                else               Cf[o] = v + bias[gcol];
            }
        }
    }
}

// ---------------------------------------------------------------------------
__global__ __launch_bounds__(256) void gemm_gu(
    const bf16* __restrict__ A, const bf16* __restrict__ BtAll,
    const int* __restrict__ offc, const int* __restrict__ perm,
    bf16* __restrict__ C)
{
    const int e = blockIdx.z;
    const int off = offc[8 + e];
    const int padCnt = offc[9 + e] - off;
    const int m0 = blockIdx.x * 128;
    if (m0 >= padCnt) return;
    __shared__ __align__(16) bf16 As[128 * 64];
    __shared__ __align__(16) bf16 Bs[128 * 64];
    const int tid = threadIdx.x;
    const int lane = tid & 63, wid = tid >> 6;
    const int l32 = lane & 31, lh2 = lane >> 5;
    const int wr = wid >> 1, wc = wid & 1;
    const int n0 = blockIdx.y * 128;
    const bf16* Bt = BtAll + (size_t)e * 2816 * 2048;

    int srow[4], sslot[4], tok[4];
    #pragma unroll
    for (int i = 0; i < 4; i++) {
        const int c = tid + 256*i;
        srow[i]  = c >> 3;
        sslot[i] = (((c & 7) ^ (srow[i] & 7)) << 3);
        int t = perm[off + m0 + srow[i]];
        tok[i] = (t < 0) ? 0 : t;
    }

    f32x16 acc[2][2];
    #pragma unroll
    for (int m = 0; m < 2; m++)
        #pragma unroll
        for (int n = 0; n < 2; n++)
            #pragma unroll
            for (int j = 0; j < 16; j++) acc[m][n][j] = 0.f;

    for (int k0 = 0; k0 < 2048; k0 += 64) {
        __syncthreads();
        #pragma unroll
        for (int i = 0; i < 4; i++) {
            load_lds16(A  + (size_t)tok[i] * 2048 + k0 + sslot[i], As + (tid + 256*i) * 8);
            load_lds16(Bt + (size_t)(n0 + srow[i]) * 2048 + k0 + sslot[i], Bs + (tid + 256*i) * 8);
        }
        __syncthreads();
        bf16x8 a[2][4], b[2][4];
        #pragma unroll
        for (int m = 0; m < 2; m++) {
            const int r = wr*64 + m*32 + l32, rx = r & 7;
            #pragma unroll
            for (int kk = 0; kk < 4; kk++)
                a[m][kk] = *(const bf16x8*)&As[r*64 + ((((kk<<1)|lh2) ^ rx) << 3)];
        }
        #pragma unroll
        for (int n = 0; n < 2; n++) {
            const int r = wc*64 + n*32 + l32, rx = r & 7;
            #pragma unroll
            for (int kk = 0; kk < 4; kk++)
                b[n][kk] = *(const bf16x8*)&Bs[r*64 + ((((kk<<1)|lh2) ^ rx) << 3)];
        }
        #pragma unroll
        for (int kk = 0; kk < 4; kk++)
            #pragma unroll
            for (int m = 0; m < 2; m++)
                #pragma unroll
                for (int n = 0; n < 2; n++)
                    acc[m][n] = __builtin_amdgcn_mfma_f32_32x32x16_bf16(a[m][kk], b[n][kk], acc[m][n], 0, 0, 0);
    }

    #pragma unroll
    for (int m = 0; m < 2; m++) {
        const int base_m = m0 + wr*64 + m*32 + 4*lh2;
        #pragma unroll
        for (int n = 0; n < 2; n++) {
            const int gcol = n0 + wc*64 + n*32 + l32;
            #pragma unroll
            for (int reg = 0; reg < 16; reg++) {
                const int grow = base_m + (reg & 3) + 8*(reg >> 2);
                C[(size_t)(off + grow) * 2816 + gcol] = f2b(acc[m][n][reg]);
            }
        }
    }
}

__global__ __launch_bounds__(256) void gemm_down(
    const bf16* __restrict__ A, const bf16* __restrict__ BtAll,
    const int* __restrict__ offc, bf16* __restrict__ Y)
{
    const int e = blockIdx.z;
    const int off = offc[8 + e];
    const int padCnt = offc[9 + e] - off;
    const int m0 = blockIdx.x * 128;
    if (m0 >= padCnt) return;
    __shared__ __align__(16) bf16 As[128 * 64];
    __shared__ __align__(16) bf16 Bs[128 * 64];
    const int tid = threadIdx.x;
    const int lane = tid & 63, wid = tid >> 6;
    const int l32 = lane & 31, lh2 = lane >> 5;
    const int wr = wid >> 1, wc = wid & 1;
    const int n0 = blockIdx.y * 128;
    const bf16* Bt = BtAll + (size_t)e * 2048 * 1408;

    int srow[4], sslot[4];
    #pragma unroll
    for (int i = 0; i < 4; i++) {
        const int c = tid + 256*i;
        srow[i]  = c >> 3;
        sslot[i] = (((c & 7) ^ (srow[i] & 7)) << 3);
    }

    f32x16 acc[2][2];
    #pragma unroll
    for (int m = 0; m < 2; m++)
        #pragma unroll
        for (int n = 0; n < 2; n++)
            #pragma unroll
            for (int j = 0; j < 16; j++) acc[m][n][j] = 0.f;

    for (int k0 = 0; k0 < 1408; k0 += 64) {
        __syncthreads();
        #pragma unroll
        for (int i = 0; i < 4; i++) {
            load_lds16(A  + (size_t)(off + m0 + srow[i]) * 1408 + k0 + sslot[i], As + (tid + 256*i) * 8);
            load_lds16(Bt + (size_t)(n0 + srow[i]) * 1408 + k0 + sslot[i], Bs + (tid + 256*i) * 8);
        }
        __syncthreads();
        bf16x8 a[2][4], b[2][4];
        #pragma unroll
        for (int m = 0; m < 2; m++) {
            const int r = wr*64 + m*32 + l32, rx = r & 7;
            #pragma unroll
            for (int kk = 0; kk < 4; kk++)
                a[m][kk] = *(const bf16x8*)&As[r*64 + ((((kk<<1)|lh2) ^ rx) << 3)];
        }
        #pragma unroll
        for (int n = 0; n < 2; n++) {
            const int r = wc*64 + n*32 + l32, rx = r & 7;
            #pragma unroll
            for (int kk = 0; kk < 4; kk++)
                b[n][kk] = *(const bf16x8*)&Bs[r*64 + ((((kk<<1)|lh2) ^ rx) << 3)];
        }
        #pragma unroll
        for (int kk = 0; kk < 4; kk++)
            #pragma unroll
            for (int m = 0; m < 2; m++)
                #pragma unroll
                for (int n = 0; n < 2; n++)
                    acc[m][n] = __builtin_amdgcn_mfma_f32_32x32x16_bf16(a[m][kk], b[n][kk], acc[m][n], 0, 0, 0);
    }

    #pragma unroll
    for (int m = 0; m < 2; m++) {
        const int base_m = m0 + wr*64 + m*32 + 4*lh2;
        #pragma unroll
        for (int n = 0; n < 2; n++) {
            const int gcol = n0 + wc*64 + n*32 + l32;
            #pragma unroll
            for (int reg = 0; reg < 16; reg++) {
                const int grow = base_m + (reg & 3) + 8*(reg >> 2);
                Y[(size_t)(off + grow) * 2048 + gcol] = f2b(acc[m][n][reg]);
            }
        }
    }
}

// ---------------------------------------------------------------------------
__global__ void rope_table_k(float2* __restrict__ cs)
{
    const int i = blockIdx.x * 256 + threadIdx.x;   // < 65536
    const int s = i >> 6, d = i & 63;
    const float fr = (float)s * powf(1.0e6f, -(float)d * (1.0f / 64.0f));
    float c, sn;
    sincosf(fr, &sn, &c);
    cs[i] = make_float2(c, sn);
}

__global__ void rope_f32_k(float* __restrict__ qkv, const float2* __restrict__ cs)
{
    const int idx = blockIdx.x * 256 + threadIdx.x;
    const int d  = idx & 63;
    const int hh = (idx >> 6) & 15;
    const size_t base = (size_t)(idx >> 10) * 6144 + hh * HD;
    const int s = (idx >> 10) & 1023;
    const float2 t = cs[(s << 6) | d];
    const float c = t.x, sn = t.y;
    float q0 = qkv[base + d], q1 = qkv[base + d + 64];
    qkv[base + d]      = q0 * c - q1 * sn;
    qkv[base + d + 64] = q1 * c + q0 * sn;
    float k0 = qkv[base + 2048 + d], k1 = qkv[base + 2048 + d + 64];
    qkv[base + 2048 + d]      = k0 * c - k1 * sn;
    qkv[base + 2048 + d + 64] = k1 * c + k0 * sn;
}

// ---------------------------------------------------------------------------
__global__ __launch_bounds__(256) void transpose_v3_k(
    const float* __restrict__ qkv, bf16* __restrict__ vth, bf16* __restrict__ vtl)
{
    __shared__ float t[32][33];
    const int s0 = blockIdx.x * 32, d0 = blockIdx.y * 32;
    const int bh = blockIdx.z, b = bh >> 4, h = bh & 15;
    const int tx = threadIdx.x & 31, ty = threadIdx.x >> 5;
    const float* vb = qkv + ((size_t)b * SEQ) * 6144 + 4096 + h * HD;
    #pragma unroll
    for (int i = 0; i < 4; i++)
        t[ty + i*8][tx] = vb[(size_t)(s0 + ty + i*8) * 6144 + d0 + tx];
    __syncthreads();
    const size_t ob = ((size_t)bh * HD) * SEQ;
    #pragma unroll
    for (int i = 0; i < 4; i++) {
        float val = t[tx][ty + i*8];
        bf16 h2_ = f2b(val);
        bf16 l2_ = f2b(val - b2f(h2_));
        const size_t o = ob + (size_t)(d0 + ty + i*8) * SEQ + s0 + tx;
        vth[o] = h2_;
        vtl[o] = l2_;
    }
}

// ---------------------------------------------------------------------------
// Flash attention, causal, 2-limb, KVBLK=64, XOR-swizzled K/V/P LDS.
__global__ __launch_bounds__(256) void attn3_k(
    const float* __restrict__ qkv,
    const bf16* __restrict__ vthg, const bf16* __restrict__ vtlg,
    bf16* __restrict__ ctx2)
{
    __shared__ __align__(16) bf16 SM[32768];   // 64 KB
    bf16* Ksh = SM;
    bf16* Ksl = SM + 8192;
    bf16* Vth = SM + 16384;
    bf16* Vtl = SM + 24576;
    bf16* Ph  = SM;
    bf16* Pl  = SM + 4096;

    const int tid = threadIdx.x, lane = tid & 63, wid = tid >> 6;
    const int l16 = lane & 15, lh = lane >> 4;
    const int bh = blockIdx.y, b = bh >> 4, h = bh & 15;
    const int qbase = blockIdx.x * 64;
    const int qw = qbase + wid * 16;
    const float* qp = qkv + ((size_t)b * SEQ) * 6144 + h * HD;
    const float* kp = qkv + ((size_t)b * SEQ) * 6144 + 2048 + h * HD;
    const bf16* vph = vthg + ((size_t)bh * HD) * SEQ;
    const bf16* vpl = vtlg + ((size_t)bh * HD) * SEQ;

    bf16x8 aqh[4], aql[4];
    #pragma unroll
    for (int c = 0; c < 4; c++) {
        const float* qrow = qp + (size_t)(qw + l16) * 6144 + c*32 + lh*8;
        #pragma unroll
        for (int u = 0; u < 8; u++) {
            bf16 hh_ = f2b(qrow[u]);
            bf16 ll_ = f2b(qrow[u] - b2f(hh_));
            aqh[c][u] = __builtin_bit_cast(short, hh_);
            aql[c][u] = __builtin_bit_cast(short, ll_);
        }
    }

    f32x4 o[8];
    #pragma unroll
    for (int n = 0; n < 8; n++) o[n] = (f32x4){0.f, 0.f, 0.f, 0.f};
    float mj[4], lj[4];
    #pragma unroll
    for (int j = 0; j < 4; j++) { mj[j] = -1e30f; lj[j] = 0.f; }

    const int kr = tid >> 2;
    const int kc = (tid & 3) * 32;
    const int krx = kr & 15;
    const int kt_end = blockIdx.x + 1;
    for (int kt = 0; kt < kt_end; ++kt) {
        const int kv0 = kt * 64;
        __syncthreads();
        {
            const float* krow = kp + (size_t)(kv0 + kr) * 6144 + kc;
            #pragma unroll
            for (int u = 0; u < 8; u++) {
                float4 kv4 = *(const float4*)(krow + u*4);
                bf16x4 h4, l4;
                #pragma unroll
                for (int j = 0; j < 4; j++) {
                    const float vv = ((const float*)&kv4)[j];
                    bf16 hh_ = f2b(vv);
                    bf16 ll_ = f2b(vv - b2f(hh_));
                    h4[j] = __builtin_bit_cast(short, hh_);
                    l4[j] = __builtin_bit_cast(short, ll_);
                }
                const int s = (((kc + u*4) >> 3) ^ krx);
                const int dst = kr*128 + (s << 3) + ((u & 1) * 4);
                *(bf16x4*)&Ksh[dst] = h4;
                *(bf16x4*)&Ksl[dst] = l4;
            }
        }
        #pragma unroll
        for (int i = 0; i < 4; i++) {
            const int c = tid + 256*i;
            const int row = c >> 3, sl = (c & 7) ^ (row & 7);
            load_lds16(vph + (size_t)row * SEQ + kv0 + (sl << 3), Vth + c*8);
            load_lds16(vpl + (size_t)row * SEQ + kv0 + (sl << 3), Vtl + c*8);
        }
        __syncthreads();

        f32x4 sg[4];
        #pragma unroll
        for (int g = 0; g < 4; g++) sg[g] = (f32x4){0.f,0.f,0.f,0.f};
        __builtin_amdgcn_s_setprio(1);
        #pragma unroll
        for (int c = 0; c < 4; c++) {
            #pragma unroll
            for (int g = 0; g < 4; g++) {
                const int row = l16 + g*16;
                const int sl = (((c*4 + lh) ^ (row & 15)) << 3);
                bf16x8 bkh = *(const bf16x8*)&Ksh[row*128 + sl];
                bf16x8 bkl = *(const bf16x8*)&Ksl[row*128 + sl];
                sg[g] = __builtin_amdgcn_mfma_f32_16x16x32_bf16(aqh[c], bkh, sg[g], 0, 0, 0);
                sg[g] = __builtin_amdgcn_mfma_f32_16x16x32_bf16(aql[c], bkh, sg[g], 0, 0, 0);
                sg[g] = __builtin_amdgcn_mfma_f32_16x16x32_bf16(aqh[c], bkl, sg[g], 0, 0, 0);
            }
        }
        __builtin_amdgcn_s_setprio(0);
        __syncthreads();

        const float scale = 0.08838834764831845f;
        #pragma unroll
        for (int j = 0; j < 4; j++) {
            const int qrow = qw + lh*4 + j;
            float sv[4];
            #pragma unroll
            for (int g = 0; g < 4; g++) {
                sv[g] = sg[g][j] * scale;
                if (kv0 + l16 + g*16 > qrow) sv[g] = -1e30f;
            }
            float mx = fmaxf(fmaxf(sv[0], sv[1]), fmaxf(sv[2], sv[3]));
            #pragma unroll
            for (int off = 1; off < 16; off <<= 1) mx = fmaxf(mx, __shfl_xor(mx, off, 16));
            const float nm = fmaxf(mj[j], mx);
            const float al = __expf(mj[j] - nm);
            float pg[4], rs = 0.f;
            #pragma unroll
            for (int g = 0; g < 4; g++) { pg[g] = __expf(sv[g] - nm); rs += pg[g]; }
            #pragma unroll
            for (int off = 1; off < 16; off <<= 1) rs += __shfl_xor(rs, off, 16);
            lj[j] = lj[j] * al + rs;
            mj[j] = nm;
            #pragma unroll
            for (int n = 0; n < 8; n++) o[n][j] *= al;
            const int prow = lh*4 + j;
            #pragma unroll
            for (int g = 0; g < 4; g++) {
                bf16 hh_ = f2b(pg[g]);
                bf16 ll_ = f2b(pg[g] - b2f(hh_));
                const int col = l16 + g*16;
                const int addr = wid*1024 + prow*64 + ((((col >> 3) ^ (prow & 7)) << 3)) + (col & 7);
                Ph[addr] = hh_;
                Pl[addr] = ll_;
            }
        }
        __builtin_amdgcn_s_setprio(1);
        #pragma unroll
        for (int ks = 0; ks < 2; ks++) {
            const int psl = (((ks*4 + lh) ^ (l16 & 7)) << 3);
            bf16x8 aph = *(const bf16x8*)&Ph[wid*1024 + l16*64 + psl];
            bf16x8 apl = *(const bf16x8*)&Pl[wid*1024 + l16*64 + psl];
            #pragma unroll
            for (int n = 0; n < 8; n++) {
                const int row = n*16 + l16;
                const int vsl = (((ks*4 + lh) ^ (row & 7)) << 3);
                bf16x8 bvh = *(const bf16x8*)&Vth[row*64 + vsl];
                bf16x8 bvl = *(const bf16x8*)&Vtl[row*64 + vsl];
                o[n] = __builtin_amdgcn_mfma_f32_16x16x32_bf16(aph, bvh, o[n], 0, 0, 0);
                o[n] = __builtin_amdgcn_mfma_f32_16x16x32_bf16(apl, bvh, o[n], 0, 0, 0);
                o[n] = __builtin_amdgcn_mfma_f32_16x16x32_bf16(aph, bvl, o[n], 0, 0, 0);
            }
        }
        __builtin_amdgcn_s_setprio(0);
    }

    float inv[4];
    #pragma unroll
    for (int j = 0; j < 4; j++) inv[j] = 1.0f / lj[j];
    #pragma unroll
    for (int n = 0; n < 8; n++)
        #pragma unroll
        for (int j = 0; j < 4; j++) {
            const float v = o[n][j] * inv[j];
            bf16 hh_ = f2b(v);
            bf16 ll_ = f2b(v - b2f(hh_));
            const size_t base = ((size_t)b * SEQ + (qw + lh*4 + j)) * 4096 + h * HD + n*16 + l16;
            ctx2[base]        = hh_;
            ctx2[base + 2048] = ll_;
        }
}

// ---------------------------------------------------------------------------
__global__ __launch_bounds__(256) void combine_rms_router_k(
    const float* __restrict__ x, const float* __restrict__ xp,
    const float* __restrict__ wln, const float* __restrict__ wr,
    const float* __restrict__ weg,
    float* __restrict__ x1, bf16* __restrict__ h2,
    float* __restrict__ comb, float* __restrict__ sigeg)
{
    const int row = blockIdx.x, tid = threadIdx.x;
    const size_t rb = (size_t)row * HIDDEN;
    const long zs = (long)TOKENS * HIDDEN;
    __shared__ float ps[4];
    __shared__ float pacc[4][9];
    float4 v[2];
    #pragma unroll
    for (int u = 0; u < 2; u++) {
        const int i = tid + u * 256;
        float4 a  = ((const float4*)(x + rb))[i];
        float4 p0 = ((const float4*)(xp + rb))[i];
        float4 p1 = ((const float4*)(xp + zs + rb))[i];
        float4 p2 = ((const float4*)(xp + 2*zs + rb))[i];
        v[u].x = a.x + p0.x + p1.x + p2.x;
        v[u].y = a.y + p0.y + p1.y + p2.y;
        v[u].z = a.z + p0.z + p1.z + p2.z;
        v[u].w = a.w + p0.w + p1.w + p2.w;
        ((float4*)(x1 + rb))[i] = v[u];
    }
    float ss = v[0].x*v[0].x + v[0].y*v[0].y + v[0].z*v[0].z + v[0].w*v[0].w
             + v[1].x*v[1].x + v[1].y*v[1].y + v[1].z*v[1].z + v[1].w*v[1].w;
    #pragma unroll
    for (int off = 1; off < 64; off <<= 1) ss += __shfl_xor(ss, off);
    if ((tid & 63) == 0) ps[tid >> 6] = ss;
    __syncthreads();
    const float tot = ps[0] + ps[1] + ps[2] + ps[3];
    const float r = rsqrtf(tot * (1.0f / HIDDEN) + 1e-6f);

    float acc[9];
    #pragma unroll
    for (int e = 0; e < 9; e++) acc[e] = 0.f;
    #pragma unroll
    for (int u = 0; u < 2; u++) {
        const int i = (tid + u * 256) * 4;
        const float vv[4] = {v[u].x, v[u].y, v[u].z, v[u].w};
        #pragma unroll
        for (int q = 0; q < 4; q++) {
            const float hv = vv[q] * r * wln[i + q];
            h2[rb + i + q] = f2b(hv);
            const float* wrow = wr + (size_t)(i + q) * 8;
            #pragma unroll
            for (int e = 0; e < 8; e++) acc[e] += hv * wrow[e];
            acc[8] += hv * weg[i + q];
        }
    }
    #pragma unroll
    for (int e = 0; e < 9; e++)
        #pragma unroll
        for (int off = 1; off < 64; off <<= 1) acc[e] += __shfl_xor(acc[e], off);
    if ((tid & 63) == 0)
        #pragma unroll
        for (int e = 0; e < 9; e++) pacc[tid >> 6][e] = acc[e];
    __syncthreads();
    if (tid == 0) {
        float lg[9];
        #pragma unroll
        for (int e = 0; e < 9; e++) lg[e] = pacc[0][e] + pacc[1][e] + pacc[2][e] + pacc[3][e];
        float mx = lg[0];
        #pragma unroll
        for (int e = 1; e < 8; e++) mx = fmaxf(mx, lg[e]);
        float p[8], s = 0.f;
        #pragma unroll
        for (int e = 0; e < 8; e++) { p[e] = expf(lg[e] - mx); s += p[e]; }
        const float invs = 1.0f / s;
        #pragma unroll
        for (int e = 0; e < 8; e++) p[e] *= invs;
        int i1 = 0;
        #pragma unroll
        for (int e = 1; e < 8; e++) if (p[e] > p[i1]) i1 = e;
        int i2 = (i1 == 0) ? 1 : 0;
        #pragma unroll
        for (int e = 0; e < 8; e++) if (e != i1 && p[e] > p[i2]) i2 = e;
        #pragma unroll
        for (int e = 0; e < 8; e++)
            comb[(size_t)row * 8 + e] = (e == i1 || e == i2) ? p[e] : 0.f;
        sigeg[row] = 1.0f / (1.0f + expf(-lg[8]));
    }
}

// ---------------------------------------------------------------------------
__global__ __launch_bounds__(256) void count_fill_k(
    const float* __restrict__ comb, int* __restrict__ offc, int* __restrict__ perm,
    float* __restrict__ scale, int* __restrict__ inv)
{
    __shared__ int cnt[8], off[9], fil[8];
    const int tid = threadIdx.x;
    if (tid < 8) { cnt[tid] = 0; fil[tid] = 0; }
    __syncthreads();
    for (int t = tid; t < TOKENS; t += 256)
        #pragma unroll
        for (int e = 0; e < 8; e++)
            if (comb[(size_t)t * 8 + e] > 0.f) atomicAdd(&cnt[e], 1);
    __syncthreads();
    if (tid == 0) {
        off[0] = 0;
        for (int e = 0; e < 8; e++) off[e+1] = off[e] + ((cnt[e] + 127) & ~127);
    }
    __syncthreads();
    for (int i = tid; i < MAXROWS; i += 256) { perm[i] = -1; scale[i] = 0.f; }
    __syncthreads();
    for (int t = tid; t < TOKENS; t += 256) {
        int j = 0;
        #pragma unroll
        for (int e = 0; e < 8; e++) {
            const float c = comb[(size_t)t * 8 + e];
            if (c > 0.f) {
                int s = atomicAdd(&fil[e], 1);
                int slot = off[e] + s;
                perm[slot] = t;
                scale[slot] = c;
                inv[t * 2 + j] = slot;
                j++;
            }
        }
    }
    __syncthreads();
    if (tid < 9) offc[8 + tid] = off[tid];
}

// ---------------------------------------------------------------------------
__global__ void silu_k(const bf16* __restrict__ g, bf16* __restrict__ a,
                       const float* __restrict__ rowScale,
                       int I, int ldg, int rowsConst, const int* __restrict__ rowsPtr)
{
    const int idx = (blockIdx.x * 256 + threadIdx.x) * 4;
    const int rows = rowsPtr ? *rowsPtr : rowsConst;
    const int row = idx / I;
    if (row >= rows) return;
    const int col = idx - row * I;
    const float s = rowScale[row];
    const bf16* gr = g + (size_t)row * ldg + col;
    bf16* ar = a + (size_t)row * I + col;
    #pragma unroll
    for (int c = 0; c < 4; c++) {
        const float gv = b2f(gr[c]), uv = b2f(gr[I + c]);
        ar[c] = f2b(s * gv / (1.0f + __expf(-gv)) * uv);
    }
}

// ---------------------------------------------------------------------------
__global__ void final_k(const float* __restrict__ x1, const bf16* __restrict__ y,
                        const int* __restrict__ inv, const float* __restrict__ ysh,
                        float* __restrict__ out)
{
    const int i = blockIdx.x * 256 + threadIdx.x;
    const int t = i >> 9;
    const int col = (i & 511) * 4;
    const int s0 = inv[t*2], s1 = inv[t*2 + 1];
    const long zs = (long)TOKENS * HIDDEN;
    float4 a  = ((const float4*)x1)[i];
    float4 h0 = ((const float4*)ysh)[i];
    float4 h1 = ((const float4*)(ysh + zs))[i];
    const bf16* y0 = y + (size_t)s0 * 2048 + col;
    const bf16* y1 = y + (size_t)s1 * 2048 + col;
    float4 r;
    r.x = a.x + h0.x + h1.x + b2f(y0[0]) + b2f(y1[0]);
    r.y = a.y + h0.y + h1.y + b2f(y0[1]) + b2f(y1[1]);
    r.z = a.z + h0.z + h1.z + b2f(y0[2]) + b2f(y1[2]);
    r.w = a.w + h0.w + h1.w + b2f(y0[3]) + b2f(y1[3]);
    ((float4*)out)[i] = r;
}

// ---------------------------------------------------------------------------
extern "C" void kernel_launch(void* const* d_in, const int* in_sizes, int n_in,
                              void* d_out, int out_size, void* d_ws, size_t ws_size,
                              hipStream_t stream)
{
    const float* x     = (const float*)d_in[0];
    const float* w_ln1 = (const float*)d_in[1];
    const float* wq    = (const float*)d_in[2];
    const float* bq    = (const float*)d_in[3];
    const float* wk    = (const float*)d_in[4];
    const float* bk    = (const float*)d_in[5];
    const float* wv    = (const float*)d_in[6];
    const float* bv    = (const float*)d_in[7];
    const float* wo    = (const float*)d_in[8];
    const float* w_ln2 = (const float*)d_in[9];
    const float* w_rt  = (const float*)d_in[10];
    const float* w_ge  = (const float*)d_in[11];
    const float* w_ue  = (const float*)d_in[12];
    const float* w_de  = (const float*)d_in[13];
    const float* w_sg  = (const float*)d_in[14];
    const float* w_su  = (const float*)d_in[15];
    const float* w_sd  = (const float*)d_in[16];
    const float* w_eg  = (const float*)d_in[17];
    float* out = (float*)d_out;
    (void)in_sizes; (void)n_in; (void)out_size; (void)ws_size;

    char* ws = (char*)d_ws;
    float* x1    = (float*)(ws + 0);
    bf16*  h2    = (bf16*)(ws + 16777216);
    float* comb  = (float*)(ws + 25165824);
    float* seg   = (float*)(ws + 25231360);
    int*   offc  = (int*)(ws + 25239552);
    float* scale = (float*)(ws + 25243648);
    int*   perm  = (int*)(ws + 25276416);
    int*   inv   = (int*)(ws + 25297920);
    float* bqkv  = (float*)(ws + 25314304);
    float2* ropecs = (float2*)(ws + 25338880);
    const size_t S = 25863168;
    // phase A
    bf16*  hcat  = (bf16*)(ws + S);
    bf16*  wtqkv = (bf16*)(ws + S + 16777216);
    float* qkvf  = (float*)(ws + S + 67108864);
    bf16*  wt3o  = (bf16*)(ws + S + 117440512);
    bf16*  vth   = (bf16*)(ws + S);
    bf16*  vtl   = (bf16*)(ws + S + 8388608);
    bf16*  ctx2  = (bf16*)(ws + S + 16777216);
    float* xp    = (float*)(ws + S + 50331648);
    // phase B
    bf16*  wtgu  = (bf16*)(ws + S);
    bf16*  gb    = (bf16*)(ws + S + 92274688);
    bf16*  ab    = (bf16*)(ws + S);
    bf16*  wtd   = (bf16*)(ws + S + 14417920);
    bf16*  ymoe  = (bf16*)(ws + S + 60555264);
    // phase C
    bf16*  wtshgu = (bf16*)(ws + S);
    bf16*  gsh    = (bf16*)(ws + S + 81526784);
    bf16*  ash    = (bf16*)(ws + S);
    bf16*  wtshd  = (bf16*)(ws + S + 23068672);
    float* ysh    = (float*)(ws + S + 81526784);

    // 1) RMSNorm1 -> hcat; QKV bias concat; rope table
    rmsnorm3_k<<<TOKENS, 256, 0, stream>>>(x, w_ln1, hcat);
    (void)hipMemcpyAsync(bqkv,        bq, 8192, hipMemcpyDeviceToDevice, stream);
    (void)hipMemcpyAsync(bqkv + 2048, bk, 8192, hipMemcpyDeviceToDevice, stream);
    (void)hipMemcpyAsync(bqkv + 4096, bv, 8192, hipMemcpyDeviceToDevice, stream);
    rope_table_k<<<256, 256, 0, stream>>>(ropecs);

    // 2) All 4 attention weight transposes in one launch; fused QKV GEMM
    transpose_qkvo_k<<<dim3(64, 64, 4), 256, 0, stream>>>(wq, wk, wv, wo, wtqkv, wt3o);
    gemm_bt<<<dim3(16, 48, 1), 256, 0, stream>>>(hcat, wtqkv, qkvf, nullptr, bqkv,
                                                 TOKENS, 6144, K3, 4096, 4096, 6144, 0, 1, 5);

    // 3) RoPE + V transpose/split + attention (KVBLK=64, swizzled)
    rope_f32_k<<<8192, 256, 0, stream>>>(qkvf, ropecs);
    transpose_v3_k<<<dim3(32, 4, 32), 256, 0, stream>>>(qkvf, vth, vtl);
    attn3_k<<<dim3(16, 32), 256, 0, stream>>>(qkvf, vth, vtl, ctx2);

    // 4) O-proj (limb3, split-K z=3, plain stores) + fused combine/rms/router
    gemm_bt<<<dim3(16, 16, 3), 256, 0, stream>>>(ctx2, wt3o, xp, nullptr, nullptr,
                                                 TOKENS, HIDDEN, 2048, 4096, 4096, 2048,
                                                 (long)TOKENS * HIDDEN, 1, 4);
    combine_rms_router_k<<<TOKENS, 256, 0, stream>>>(x, xp, w_ln2, w_rt, w_eg,
                                                     x1, h2, comb, seg);
    count_fill_k<<<1, 256, 0, stream>>>(comb, offc, perm, scale, inv);

    // 5) Sparse MoE
    transpose_moegu_k<<<dim3(44, 64, 16), 256, 0, stream>>>(w_ge, w_ue, wtgu);
    gemm_gu<<<dim3(MAXROWS/128, 22, 8), 256, 0, stream>>>(h2, wtgu, offc, perm, gb);
    silu_k<<<(MAXROWS * MOE_I) / 1024, 256, 0, stream>>>(gb, ab, scale, MOE_I, 2816, 0, offc + 16);
    transpose_wz<<<dim3(64, 44, 8), 256, 0, stream>>>(w_de, wtd, MOE_I, HIDDEN, 0,
                                                      (long)MOE_I*HIDDEN, (long)HIDDEN*MOE_I);
    gemm_down<<<dim3(MAXROWS/128, 16, 8), 256, 0, stream>>>(ab, wtd, offc, ymoe);

    // 6) Shared expert
    transpose_shgu_k<<<dim3(176, 64, 2), 256, 0, stream>>>(w_sg, w_su, wtshgu);
    gemm_bt<<<dim3(16, 88, 1), 256, 0, stream>>>(h2, wtshgu, nullptr, gsh, nullptr,
                                                 TOKENS, 2*SH_I, HIDDEN, HIDDEN, HIDDEN, 2*SH_I, 0, 0, 0);
    silu_k<<<(TOKENS * SH_I) / 1024, 256, 0, stream>>>(gsh, ash, seg, SH_I, 2*SH_I, TOKENS, nullptr);
    transpose_wz<<<dim3(64, 176, 1), 256, 0, stream>>>(w_sd, wtshd, SH_I, HIDDEN, 0, 0, 0);
    gemm_bt<<<dim3(16, 16, 2), 256, 0, stream>>>(ash, wtshd, ysh, nullptr, nullptr,
                                                 TOKENS, HIDDEN, SH_I/2, SH_I, SH_I, 2048,
                                                 (long)TOKENS * HIDDEN, 0, 4);

    // 7) Final gather-sum
    final_k<<<(TOKENS * HIDDEN) / 1024, 256, 0, stream>>>(x1, ymoe, inv, ysh, out);
}